// Round 4
// baseline (111.799 us; speedup 1.0000x reference)
//
#include <hip/hip_runtime.h>

// QOuter: out_rr[b,i,j] = real[b,i]*real[b,j] + imag[b,i]*imag[b,j]
//         out_ii[b,i,j] = imag[b,i]*real[b,j] - real[b,i]*imag[b,j]
// B=64, N=1024. Outputs concatenated flat: [out_rr (B*N*N), out_ii (B*N*N)].
// Store-BW bound. This round: each block writes ONE output tensor only
// (single contiguous 64KB stream per block) instead of ping-ponging between
// out_rr and out_ii 256MB apart. Grid halves: [0,8192) -> rr, [8192,16384) -> ii.

typedef float f32x4 __attribute__((ext_vector_type(4)));

constexpr int B_ = 64;
constexpr int N_ = 1024;
constexpr int ROWS = 16;                // rows (i values) per block

__global__ __launch_bounds__(256) void qouter_kernel(
    const float* __restrict__ real,
    const float* __restrict__ imag,
    float* __restrict__ out) {
    constexpr int BLKS_PER_OUT = B_ * (N_ / ROWS);      // 64*64 = 4096
    const int blk  = blockIdx.x;
    const bool ii_side = blk >= BLKS_PER_OUT;           // block-uniform
    const int blk2 = ii_side ? blk - BLKS_PER_OUT : blk;
    const int b    = blk2 >> 6;                         // blk2 / (N/ROWS)
    const int i0   = (blk2 & 63) * ROWS;                // first row of strip
    const int t    = threadIdx.x;                       // one float4 of row j

    const float* rrow = real + (size_t)b * N_;
    const float* irow = imag + (size_t)b * N_;

    // Row vectors (j-direction), loaded once, registers for all 16 rows
    const f32x4 rj = reinterpret_cast<const f32x4*>(rrow)[t];
    const f32x4 ij = reinterpret_cast<const f32x4*>(irow)[t];

    f32x4* out4  = reinterpret_cast<f32x4*>(out);
    size_t f4    = ((size_t)b * N_ + i0) * (N_ / 4) + t;
    if (ii_side) f4 += (size_t)B_ * N_ * (N_ / 4);      // out_ii base

    if (!ii_side) {
#pragma unroll
        for (int r = 0; r < ROWS; ++r) {
            const float rc = rrow[i0 + r];
            const float ic = irow[i0 + r];
            f32x4 orr = rc * rj + ic * ij;
            __builtin_nontemporal_store(orr, out4 + f4);
            f4 += N_ / 4;
        }
    } else {
#pragma unroll
        for (int r = 0; r < ROWS; ++r) {
            const float rc = rrow[i0 + r];
            const float ic = irow[i0 + r];
            f32x4 oii = ic * rj - rc * ij;
            __builtin_nontemporal_store(oii, out4 + f4);
            f4 += N_ / 4;
        }
    }
}

extern "C" void kernel_launch(void* const* d_in, const int* in_sizes, int n_in,
                              void* d_out, int out_size, void* d_ws, size_t ws_size,
                              hipStream_t stream) {
    const float* real = (const float*)d_in[0];
    const float* imag = (const float*)d_in[1];
    float* out = (float*)d_out;

    dim3 grid(2 * B_ * (N_ / ROWS));   // 8192 blocks: 4096 rr + 4096 ii
    dim3 block(256);                   // 256 threads x float4 = 1024 columns
    qouter_kernel<<<grid, block, 0, stream>>>(real, imag, out);
}